// Round 1
// baseline (96.673 us; speedup 1.0000x reference)
//
#include <hip/hip_runtime.h>
#include <hip/hip_bf16.h>

// ContrastiveLoss (NT-Xent): B=2048, D=256, T=0.5
// loss = mean_i [ -2*dot(zh_i, zh_pos(i)) + log( sum_j exp(2*dot(zh_i, zh_j)) - e^2 ) ]
// Symmetric Gram, upper-triangular 128x64 tiles (1056 blocks; was 528x 128x128).
// k_sim v2: NO LDS staging / NO per-strip barriers -- B fragments stream straight
// from L2 (zb is 2MB, fully L2-resident; staging was pure overhead at 2 blocks/CU).
// Finer tiles double scheduler parallelism (4.1 blocks/CU). Off-diagonal tiles add
// row sums AND column sums (via tiny LDS cs[64], 2 barriers total) into S[4096].
// A-side bf16 copy pre-scaled by 2*log2(e) so exp(2*sim) = exp2(dot) -> bare v_exp_f32.

typedef __attribute__((ext_vector_type(8))) short short8;
typedef __attribute__((ext_vector_type(4))) float float4v;

#define NROWS 4096
#define DIM 256
#define NB 2048
#define TEMP_INV 2.0f
#define SCALE 2.8853900817779268f  // 2*log2(e)
#define NTILES 1056  // sum_{ib=0}^{31} (64 - 2*ib) upper-triangular 128x64 tiles

static __device__ __forceinline__ unsigned short f2bf_rne(float f) {
    unsigned int x = __float_as_uint(f);
    unsigned int r = x + 0x7FFFu + ((x >> 16) & 1u);
    return (unsigned short)(r >> 16);
}

// K1: normalize pair (p, p+NB); write zb (bf16), zb2 (bf16 * 2log2e), pos-dot pd[p].
// Also zero S and out. grid 512 x 256.
__global__ __launch_bounds__(256) void k_norm(const float* __restrict__ zi,
                                              const float* __restrict__ zj,
                                              unsigned short* __restrict__ zb,
                                              unsigned short* __restrict__ zb2,
                                              float* __restrict__ pd,
                                              float* __restrict__ S,
                                              float* __restrict__ out) {
    if (blockIdx.x == 0 && threadIdx.x == 0) *out = 0.0f;
    if (threadIdx.x < 8) S[blockIdx.x * 8 + threadIdx.x] = 0.0f;
    int wave = threadIdx.x >> 6, lane = threadIdx.x & 63;
    int p = blockIdx.x * 4 + wave;  // pair index, rows p and p+NB
    float4 vi = *(const float4*)(zi + (size_t)p * DIM + lane * 4);
    float4 vj = *(const float4*)(zj + (size_t)p * DIM + lane * 4);
    float ssi = vi.x * vi.x + vi.y * vi.y + vi.z * vi.z + vi.w * vi.w;
    float ssj = vj.x * vj.x + vj.y * vj.y + vj.z * vj.z + vj.w * vj.w;
    float dij = vi.x * vj.x + vi.y * vj.y + vi.z * vj.z + vi.w * vj.w;
    #pragma unroll
    for (int off = 32; off > 0; off >>= 1) {
        ssi += __shfl_xor(ssi, off);
        ssj += __shfl_xor(ssj, off);
        dij += __shfl_xor(dij, off);
    }
    float si = 1.0f / fmaxf(sqrtf(ssi), 1e-12f);
    float sj = 1.0f / fmaxf(sqrtf(ssj), 1e-12f);
    ushort4 a, b;
    a.x = f2bf_rne(vi.x * si); a.y = f2bf_rne(vi.y * si);
    a.z = f2bf_rne(vi.z * si); a.w = f2bf_rne(vi.w * si);
    b.x = f2bf_rne(vj.x * sj); b.y = f2bf_rne(vj.y * sj);
    b.z = f2bf_rne(vj.z * sj); b.w = f2bf_rne(vj.w * sj);
    *(ushort4*)(zb + (size_t)p * DIM + lane * 4) = a;
    *(ushort4*)(zb + (size_t)(p + NB) * DIM + lane * 4) = b;
    float ki = si * SCALE, kj = sj * SCALE;
    ushort4 a2, b2;
    a2.x = f2bf_rne(vi.x * ki); a2.y = f2bf_rne(vi.y * ki);
    a2.z = f2bf_rne(vi.z * ki); a2.w = f2bf_rne(vi.w * ki);
    b2.x = f2bf_rne(vj.x * kj); b2.y = f2bf_rne(vj.y * kj);
    b2.z = f2bf_rne(vj.z * kj); b2.w = f2bf_rne(vj.w * kj);
    *(ushort4*)(zb2 + (size_t)p * DIM + lane * 4) = a2;
    *(ushort4*)(zb2 + (size_t)(p + NB) * DIM + lane * 4) = b2;
    if (lane == 0) pd[p] = dij * si * sj;
}

// K2 v2: upper-triangular 128x64 exp2-tiles, barrier-free streaming.
// Block = 4 waves; wave owns 32 i-rows (two 16x16 A-tiles register-resident from
// zb2). B fragments read DIRECTLY from zb via L2 (no LDS staging). Row sums
// always; col sums (via LDS cs[64]) when the tile is strictly right of the
// diagonal 128x128 block. Atomics into S.
// Tile decode: ib in [0,32) row-block of 128; jc in [2*ib, 64) col-block of 64.
// jc in {2ib, 2ib+1} are the two halves of the full diagonal tile (computed
// fully, no col sums); jc >= 2ib+2 is strictly upper -> col sums too.
__global__ __launch_bounds__(256) void k_sim(const unsigned short* __restrict__ zb,
                                             const unsigned short* __restrict__ zb2,
                                             float* __restrict__ S) {
    __shared__ float cs[64];
    int rem = blockIdx.x, ib = 0;
    while (rem >= 64 - 2 * ib) { rem -= 64 - 2 * ib; ib++; }
    int jc = 2 * ib + rem;
    bool do_col = (jc >= 2 * ib + 2);

    int tid = threadIdx.x, wave = tid >> 6, lane = tid & 63;
    int m = lane & 15, q = lane >> 4;
    const short* zsB = (const short*)zb;
    const short* zsA = (const short*)zb2;
    int ibase = ib * 128 + wave * 32;
    int jbase = jc * 64;

    if (do_col) {
        if (tid < 64) cs[tid] = 0.0f;
        __syncthreads();
    }

    // A fragments: A[m][k], m = lane&15, k = q*8 + t  (verified 16x16x32 layout)
    short8 A[2][8];
    #pragma unroll
    for (int t = 0; t < 2; t++) {
        const short* arow = zsA + (size_t)(ibase + t * 16 + m) * DIM + q * 8;
        #pragma unroll
        for (int kk = 0; kk < 8; kk++) A[t][kk] = *(const short8*)(arow + kk * 32);
    }

    float rowacc[2][4] = {{0.f, 0.f, 0.f, 0.f}, {0.f, 0.f, 0.f, 0.f}};

    #pragma unroll
    for (int jt = 0; jt < 4; jt++) {
        const short* brow = zsB + (size_t)(jbase + jt * 16 + m) * DIM + q * 8;
        float4v c0 = {0.f, 0.f, 0.f, 0.f};
        float4v c1 = {0.f, 0.f, 0.f, 0.f};
        #pragma unroll
        for (int kk = 0; kk < 8; kk++) {
            short8 b = *(const short8*)(brow + kk * 32);
            c0 = __builtin_amdgcn_mfma_f32_16x16x32_bf16(A[0][kk], b, c0, 0, 0, 0);
            c1 = __builtin_amdgcn_mfma_f32_16x16x32_bf16(A[1][kk], b, c1, 0, 0, 0);
        }
        float csum = 0.0f;
        #pragma unroll
        for (int r = 0; r < 4; r++) {
            float e0 = __builtin_exp2f(c0[r]);
            float e1 = __builtin_exp2f(c1[r]);
            rowacc[0][r] += e0; rowacc[1][r] += e1;
            csum += e0 + e1;
        }
        if (do_col) {
            // column jt*16 + m of this tile: sum over this wave's 32 rows
            csum += __shfl_xor(csum, 16);
            csum += __shfl_xor(csum, 32);
            if (lane < 16) atomicAdd(&cs[jt * 16 + m], csum);
        }
    }

    // row sums: reduce over 16 column-lanes, atomic into S
    #pragma unroll
    for (int t = 0; t < 2; t++) {
        #pragma unroll
        for (int r = 0; r < 4; r++) {
            float s = rowacc[t][r];
            s += __shfl_xor(s, 1);
            s += __shfl_xor(s, 2);
            s += __shfl_xor(s, 4);
            s += __shfl_xor(s, 8);
            if (m == 0) atomicAdd(&S[ibase + t * 16 + q * 4 + r], s);
        }
    }
    if (do_col) {
        __syncthreads();
        if (tid < 64) atomicAdd(&S[jbase + tid], cs[tid]);
    }
}

// K3: loss = mean over rows of log(S[i]-e^2) - 2*pd[i%NB]. grid 16 x 256.
__global__ __launch_bounds__(256) void k_loss(const float* __restrict__ S,
                                              const float* __restrict__ pd,
                                              float* __restrict__ out) {
    __shared__ float red[4];
    int wave = threadIdx.x >> 6, lane = threadIdx.x & 63;
    int i = blockIdx.x * 256 + threadIdx.x;
    const float E2 = 7.38905609893065f;  // exp(sim_ii) = e^2
    float term = logf(S[i] - E2) - TEMP_INV * pd[i & (NB - 1)];
    #pragma unroll
    for (int off = 32; off > 0; off >>= 1) term += __shfl_xor(term, off);
    if (lane == 0) red[wave] = term;
    __syncthreads();
    if (threadIdx.x == 0) {
        float t = (red[0] + red[1] + red[2] + red[3]) * (1.0f / NROWS);
        atomicAdd(out, t);
    }
}

extern "C" void kernel_launch(void* const* d_in, const int* in_sizes, int n_in,
                              void* d_out, int out_size, void* d_ws, size_t ws_size,
                              hipStream_t stream) {
    const float* zi = (const float*)d_in[0];
    const float* zj = (const float*)d_in[1];
    float* out = (float*)d_out;
    char* ws = (char*)d_ws;
    unsigned short* zb  = (unsigned short*)ws;                        // 2 MB bf16 normalized
    unsigned short* zb2 = (unsigned short*)(ws + 2 * 1024 * 1024);    // 2 MB bf16 * 2log2e
    float* S  = (float*)(ws + 4 * 1024 * 1024);                       // 16 KB row exp sums
    float* pd = (float*)(ws + 4 * 1024 * 1024 + 16 * 1024);           // 8 KB pos dots

    hipLaunchKernelGGL(k_norm, dim3(512), dim3(256), 0, stream, zi, zj, zb, zb2, pd, S, out);
    hipLaunchKernelGGL(k_sim, dim3(NTILES), dim3(256), 0, stream, zb, zb2, S);
    hipLaunchKernelGGL(k_loss, dim3(16), dim3(256), 0, stream, S, pd, out);
}

// Round 3
// 82.089 us; speedup vs baseline: 1.1777x; 1.1777x over previous
//
#include <hip/hip_runtime.h>
#include <hip/hip_bf16.h>

// ContrastiveLoss (NT-Xent): B=2048, D=256, T=0.5
// loss = mean_i [ -2*dot(zh_i, zh_pos(i)) + log( sum_j exp(2*dot(zh_i, zh_j)) - e^2 ) ]
// Symmetric Gram, upper-triangular 128x64 tiles (1056 blocks).
// k_sim v3: B strip (64 rows x 512B) staged via async global_load_lds width=16
// in ONE burst + ONE barrier (v1 had 5 barriers + VGPR-roundtrip staging; v2's
// direct-L2 streaming regressed: 4x redundant B reads + L2 latency on MFMA path).
// LDS layout is linear rows with XOR-swizzled 16B slots (slot ^= row&7), applied
// on the GLOBAL source side (global_load_lds writes linearly: base + lane*16) and
// on the ds_read side -- avoids the 16-way bank conflict of stride-512B rows.
// Off-diagonal tiles add row sums AND column sums (LDS cs[64]) into S[4096].
// A-side bf16 copy pre-scaled by 2*log2(e) so exp(2*sim) = exp2(dot) -> v_exp_f32.

typedef __attribute__((ext_vector_type(8))) short short8;
typedef __attribute__((ext_vector_type(4))) float float4v;

#define NROWS 4096
#define DIM 256
#define NB 2048
#define TEMP_INV 2.0f
#define SCALE 2.8853900817779268f  // 2*log2(e)
#define NTILES 1056  // sum_{ib=0}^{31} (64 - 2*ib) upper-triangular 128x64 tiles

static __device__ __forceinline__ unsigned short f2bf_rne(float f) {
    unsigned int x = __float_as_uint(f);
    unsigned int r = x + 0x7FFFu + ((x >> 16) & 1u);
    return (unsigned short)(r >> 16);
}

// K1: normalize pair (p, p+NB); write zb (bf16), zb2 (bf16 * 2log2e), pos-dot pd[p].
// Also zero S and out. grid 512 x 256.
__global__ __launch_bounds__(256) void k_norm(const float* __restrict__ zi,
                                              const float* __restrict__ zj,
                                              unsigned short* __restrict__ zb,
                                              unsigned short* __restrict__ zb2,
                                              float* __restrict__ pd,
                                              float* __restrict__ S,
                                              float* __restrict__ out) {
    if (blockIdx.x == 0 && threadIdx.x == 0) *out = 0.0f;
    if (threadIdx.x < 8) S[blockIdx.x * 8 + threadIdx.x] = 0.0f;
    int wave = threadIdx.x >> 6, lane = threadIdx.x & 63;
    int p = blockIdx.x * 4 + wave;  // pair index, rows p and p+NB
    float4 vi = *(const float4*)(zi + (size_t)p * DIM + lane * 4);
    float4 vj = *(const float4*)(zj + (size_t)p * DIM + lane * 4);
    float ssi = vi.x * vi.x + vi.y * vi.y + vi.z * vi.z + vi.w * vi.w;
    float ssj = vj.x * vj.x + vj.y * vj.y + vj.z * vj.z + vj.w * vj.w;
    float dij = vi.x * vj.x + vi.y * vj.y + vi.z * vj.z + vi.w * vj.w;
    #pragma unroll
    for (int off = 32; off > 0; off >>= 1) {
        ssi += __shfl_xor(ssi, off);
        ssj += __shfl_xor(ssj, off);
        dij += __shfl_xor(dij, off);
    }
    float si = 1.0f / fmaxf(sqrtf(ssi), 1e-12f);
    float sj = 1.0f / fmaxf(sqrtf(ssj), 1e-12f);
    ushort4 a, b;
    a.x = f2bf_rne(vi.x * si); a.y = f2bf_rne(vi.y * si);
    a.z = f2bf_rne(vi.z * si); a.w = f2bf_rne(vi.w * si);
    b.x = f2bf_rne(vj.x * sj); b.y = f2bf_rne(vj.y * sj);
    b.z = f2bf_rne(vj.z * sj); b.w = f2bf_rne(vj.w * sj);
    *(ushort4*)(zb + (size_t)p * DIM + lane * 4) = a;
    *(ushort4*)(zb + (size_t)(p + NB) * DIM + lane * 4) = b;
    float ki = si * SCALE, kj = sj * SCALE;
    ushort4 a2, b2;
    a2.x = f2bf_rne(vi.x * ki); a2.y = f2bf_rne(vi.y * ki);
    a2.z = f2bf_rne(vi.z * ki); a2.w = f2bf_rne(vi.w * ki);
    b2.x = f2bf_rne(vj.x * kj); b2.y = f2bf_rne(vj.y * kj);
    b2.z = f2bf_rne(vj.z * kj); b2.w = f2bf_rne(vj.w * kj);
    *(ushort4*)(zb2 + (size_t)p * DIM + lane * 4) = a2;
    *(ushort4*)(zb2 + (size_t)(p + NB) * DIM + lane * 4) = b2;
    if (lane == 0) pd[p] = dij * si * sj;
}

// K2 v3: upper-triangular 128x64 exp2-tiles. Block = 4 waves; wave owns 32 i-rows
// (two 16x16 A-tiles register-resident from zb2). B strip (64 rows) async-staged
// into LDS via global_load_lds, swizzled source. Row sums always; col sums when
// tile is strictly right of the diagonal 128x128 block. Atomics into S.
// Tile decode: ib in [0,32) row-block of 128; jc in [2*ib, 64) col-block of 64.
__global__ __launch_bounds__(256, 3) void k_sim(const unsigned short* __restrict__ zb,
                                                const unsigned short* __restrict__ zb2,
                                                float* __restrict__ S) {
    __shared__ __attribute__((aligned(1024))) short Bs[64 * 256];  // 32 KB, linear rows
    __shared__ float cs[64];
    int rem = blockIdx.x, ib = 0;
    while (rem >= 64 - 2 * ib) { rem -= 64 - 2 * ib; ib++; }
    int jc = 2 * ib + rem;
    bool do_col = (jc >= 2 * ib + 2);

    int tid = threadIdx.x, wave = tid >> 6, lane = tid & 63;
    int m = lane & 15, q = lane >> 4;
    const short* zsB = (const short*)zb;
    const short* zsA = (const short*)zb2;
    int ibase = ib * 128 + wave * 32;
    int jbase = jc * 64;

    if (tid < 64) cs[tid] = 0.0f;

    // Async-stage 64 B-rows (512B each) into LDS. Each global_load_lds writes
    // 1024B = 2 rows: lane l -> LDS base + l*16. Source slot is pre-swizzled
    // (slot ^ (row&7)) so the ds_read side can un-swizzle (rule: linear dest +
    // inverse-swizzled source + swizzled read).
    {
        int s = lane & 31;                 // 16B slot within row
        int rhalf = lane >> 5;             // 0 or 1
        #pragma unroll
        for (int c = 0; c < 8; c++) {
            int r = wave * 16 + c * 2 + rhalf;          // local row 0..63
            const short* gsrc = zsB + (size_t)(jbase + r) * DIM + ((s ^ (r & 7)) * 8);
            short* ldst = &Bs[(wave * 16 + c * 2) * 256];  // wave-uniform base
            __builtin_amdgcn_global_load_lds(
                (const __attribute__((address_space(1))) unsigned int*)gsrc,
                (__attribute__((address_space(3))) unsigned int*)ldst,
                16, 0, 0);
        }
    }

    // A fragments: A[m][k], m = lane&15, k = q*8 + t  (verified 16x16x32 layout)
    short8 A[2][8];
    #pragma unroll
    for (int t = 0; t < 2; t++) {
        const short* arow = zsA + (size_t)(ibase + t * 16 + m) * DIM + q * 8;
        #pragma unroll
        for (int kk = 0; kk < 8; kk++) A[t][kk] = *(const short8*)(arow + kk * 32);
    }

    asm volatile("s_waitcnt vmcnt(0)" ::: "memory");
    __syncthreads();

    float rowacc[2][4] = {{0.f, 0.f, 0.f, 0.f}, {0.f, 0.f, 0.f, 0.f}};
    int swz = m & 7;

    #pragma unroll
    for (int jt = 0; jt < 4; jt++) {
        const short* brow = &Bs[(jt * 16 + m) * 256];
        float4v c0 = {0.f, 0.f, 0.f, 0.f};
        float4v c1 = {0.f, 0.f, 0.f, 0.f};
        #pragma unroll
        for (int kk = 0; kk < 8; kk++) {
            short8 b = *(const short8*)(brow + (((q + 4 * kk) ^ swz) * 8));
            c0 = __builtin_amdgcn_mfma_f32_16x16x32_bf16(A[0][kk], b, c0, 0, 0, 0);
            c1 = __builtin_amdgcn_mfma_f32_16x16x32_bf16(A[1][kk], b, c1, 0, 0, 0);
        }
        float csum = 0.0f;
        #pragma unroll
        for (int r = 0; r < 4; r++) {
            float e0 = __builtin_exp2f(c0[r]);
            float e1 = __builtin_exp2f(c1[r]);
            rowacc[0][r] += e0; rowacc[1][r] += e1;
            csum += e0 + e1;
        }
        if (do_col) {
            // column jt*16 + m of this tile: sum over this wave's 32 rows
            csum += __shfl_xor(csum, 16);
            csum += __shfl_xor(csum, 32);
            if (lane < 16) atomicAdd(&cs[jt * 16 + m], csum);
        }
    }

    // row sums: reduce over 16 column-lanes, atomic into S
    #pragma unroll
    for (int t = 0; t < 2; t++) {
        #pragma unroll
        for (int r = 0; r < 4; r++) {
            float s = rowacc[t][r];
            s += __shfl_xor(s, 1);
            s += __shfl_xor(s, 2);
            s += __shfl_xor(s, 4);
            s += __shfl_xor(s, 8);
            if (m == 0) atomicAdd(&S[ibase + t * 16 + q * 4 + r], s);
        }
    }
    if (do_col) {
        __syncthreads();
        if (tid < 64) atomicAdd(&S[jbase + tid], cs[tid]);
    }
}

// K3: loss = mean over rows of log(S[i]-e^2) - 2*pd[i%NB]. grid 16 x 256.
__global__ __launch_bounds__(256) void k_loss(const float* __restrict__ S,
                                              const float* __restrict__ pd,
                                              float* __restrict__ out) {
    __shared__ float red[4];
    int wave = threadIdx.x >> 6, lane = threadIdx.x & 63;
    int i = blockIdx.x * 256 + threadIdx.x;
    const float E2 = 7.38905609893065f;  // exp(sim_ii) = e^2
    float term = logf(S[i] - E2) - TEMP_INV * pd[i & (NB - 1)];
    #pragma unroll
    for (int off = 32; off > 0; off >>= 1) term += __shfl_xor(term, off);
    if (lane == 0) red[wave] = term;
    __syncthreads();
    if (threadIdx.x == 0) {
        float t = (red[0] + red[1] + red[2] + red[3]) * (1.0f / NROWS);
        atomicAdd(out, t);
    }
}

extern "C" void kernel_launch(void* const* d_in, const int* in_sizes, int n_in,
                              void* d_out, int out_size, void* d_ws, size_t ws_size,
                              hipStream_t stream) {
    const float* zi = (const float*)d_in[0];
    const float* zj = (const float*)d_in[1];
    float* out = (float*)d_out;
    char* ws = (char*)d_ws;
    unsigned short* zb  = (unsigned short*)ws;                        // 2 MB bf16 normalized
    unsigned short* zb2 = (unsigned short*)(ws + 2 * 1024 * 1024);    // 2 MB bf16 * 2log2e
    float* S  = (float*)(ws + 4 * 1024 * 1024);                       // 16 KB row exp sums
    float* pd = (float*)(ws + 4 * 1024 * 1024 + 16 * 1024);           // 8 KB pos dots

    hipLaunchKernelGGL(k_norm, dim3(512), dim3(256), 0, stream, zi, zj, zb, zb2, pd, S, out);
    hipLaunchKernelGGL(k_sim, dim3(NTILES), dim3(256), 0, stream, zb, zb2, S);
    hipLaunchKernelGGL(k_loss, dim3(16), dim3(256), 0, stream, S, pd, out);
}